// Round 5
// baseline (292.583 us; speedup 1.0000x reference)
//
#include <hip/hip_runtime.h>
#include <hip/hip_bf16.h>
#include <math.h>

// SparseMLP: W=8 experts, per w: out = gelu(X @ W1 + b1) @ W2 + b2
// Round 5: cross-block-overlap GEMM. BM=256, BN=128, BK=32, 256 thr (4 waves
// 2Mx2N, wave tile 128x64 => LDS:MFMA cycle ratio 0.93), LDS 48KB (2-buf x
// (A 16KB + B 8KB)) -> 2 blocks/CU; the co-resident block's MFMA covers this
// block's barrier/drain stalls (m114 mechanism) without extra VGPRs.
// Single barrier + vmcnt(0) per K-tile (T3-minimum; stage->wait distance ~1
// full iteration >> L3 latency). LDS stored as row-PAIR interleaved 128B lines
// (row r -> line r>>1, half r&1) with XOR swizzle ((line&3)<<4): ds_read_b128
// frag reads are 2-way bank-aliased (free, m136). gload_lds keeps a linear
// dest; the global SOURCE is inverse-swizzled (rule #21).

typedef float f32x4 __attribute__((ext_vector_type(4)));
typedef short bf16x8 __attribute__((ext_vector_type(8)));
typedef short bf16x4 __attribute__((ext_vector_type(4)));
typedef unsigned short u16;

#define NW 8
#define MDIM 2048   // BHS*SEQ
#define HDIM 2048
#define FFN  1024

static __device__ __forceinline__ u16 f32_to_bf16_rn(float f) {
  union { float f; unsigned u; } v; v.f = f;
  unsigned r = v.u + 0x7FFF + ((v.u >> 16) & 1);
  return (u16)(r >> 16);
}

static __device__ __forceinline__ void gload_lds16(const void* g, void* l) {
  __builtin_amdgcn_global_load_lds(
      (const __attribute__((address_space(1))) void*)g,
      (__attribute__((address_space(3))) void*)l, 16, 0, 0);
}

// X (NW*MDIM*HDIM f32) -> bf16, vectorized 4-wide
__global__ void convert_bf16_kernel(const float* __restrict__ in,
                                    u16* __restrict__ out) {
  size_t i = (size_t)blockIdx.x * blockDim.x + threadIdx.x;  // f32x4 index
  f32x4 v = ((const f32x4*)in)[i];
  bf16x4 p;
  p[0] = (short)f32_to_bf16_rn(v.x);
  p[1] = (short)f32_to_bf16_rn(v.y);
  p[2] = (short)f32_to_bf16_rn(v.z);
  p[3] = (short)f32_to_bf16_rn(v.w);
  ((bf16x4*)out)[i] = p;
}

// in: (NW, R, C) f32  ->  out: (NW, C, R) bf16 (convert + transpose), 64x64 tile
__global__ void convert_transpose_kernel(const float* __restrict__ in,
                                         u16* __restrict__ out, int R, int C) {
  __shared__ u16 tile[64][68];
  int w = blockIdx.z;
  int c0 = blockIdx.x * 64, r0 = blockIdx.y * 64;
  int t = threadIdx.x;  // 256 threads
  const float* ip = in + (size_t)w * R * C;
  u16* op = out + (size_t)w * C * R;
  int tr = t >> 4;       // 0..15
  int tc4 = (t & 15) * 4;
#pragma unroll
  for (int j = 0; j < 4; ++j) {
    int r = tr + j * 16;
    f32x4 v = *(const f32x4*)(ip + (size_t)(r0 + r) * C + c0 + tc4);
    tile[r][tc4 + 0] = f32_to_bf16_rn(v.x);
    tile[r][tc4 + 1] = f32_to_bf16_rn(v.y);
    tile[r][tc4 + 2] = f32_to_bf16_rn(v.z);
    tile[r][tc4 + 3] = f32_to_bf16_rn(v.w);
  }
  __syncthreads();
#pragma unroll
  for (int j = 0; j < 4; ++j) {
    int c = tr + j * 16;
    bf16x4 p;
    p[0] = (short)tile[tc4 + 0][c];
    p[1] = (short)tile[tc4 + 1][c];
    p[2] = (short)tile[tc4 + 2][c];
    p[3] = (short)tile[tc4 + 3][c];
    *(bf16x4*)(op + (size_t)(c0 + c) * R + r0 + tc4) = p;
  }
}

// buffer layout (24KB): A [128 lines][128B] @0, B [64 lines][128B] @16384.
// line L holds rows {2L, 2L+1}; byte col within 64B half XOR'ed by (L&3)<<4.
#define SLOT 24576
// stage one K-tile (A: 4 sweeps, B: 2 sweeps); src pre-inverse-swizzled
#define STAGE_ALL(dst, tt)                                                    \
  do {                                                                        \
    const size_t kb_ = (size_t)(tt) * 64;                                     \
    _Pragma("unroll") for (int s_ = 0; s_ < 4; ++s_)                          \
        gload_lds16(gAs + (size_t)s_ * 64 * rowK + kb_,                       \
                    (dst) + s_ * 4096 + tid * 16);                            \
    _Pragma("unroll") for (int s_ = 0; s_ < 2; ++s_)                          \
        gload_lds16(gBs + (size_t)s_ * 64 * rowK + kb_,                       \
                    (dst) + 16384 + s_ * 4096 + tid * 16);                    \
  } while (0)

// C = op(A @ B^T + bias); A: (NW,M,K) bf16; Bt: (NW,N,K) bf16.
template <bool GELU, bool C_F32>
__global__ __launch_bounds__(256, 2) void mlp_gemm(
    const u16* __restrict__ A, const u16* __restrict__ Bt,
    const float* __restrict__ bias, void* __restrict__ Cptr,
    int M, int N, int K, int nN) {
  __shared__ __align__(16) char lds[2 * SLOT];

  const int bid = blockIdx.x;
  const int w = bid & 7;            // expert -> pinned to XCD bid%8
  const int jb = bid >> 3;
  const int m0 = (jb / nN) * 256;
  const int n0 = (jb % nN) * 128;

  const int tid = threadIdx.x;
  const int wid = tid >> 6, lane = tid & 63;
  const int wr = wid >> 1, wcn = wid & 1;   // 2 M-waves x 2 N-waves
  const int qa = lane >> 4, ra = lane & 15;

  const u16* ap = A + (size_t)w * M * K;
  const u16* btp = Bt + (size_t)w * N * K;
  const float* bp = bias + (size_t)w * N;

  const size_t rowK = (size_t)K * 2;        // bytes per K-row
  // staging source map (inverse of {line/half interleave + XOR swizzle})
  const int rowbase = ((tid >> 3) << 1) + ((tid >> 2) & 1);
  const int colb = ((tid & 3) * 16) ^ (((tid >> 3) & 3) << 4);
  const char* gAs = (const char*)ap + (size_t)(m0 + rowbase) * rowK + colb;
  const char* gBs = (const char*)btp + (size_t)(n0 + rowbase) * rowK + colb;

  // fragment-read swizzled byte offset within a 128B line
  const int swz = ((ra & 1) * 64) + ((qa * 16) ^ (((ra >> 1) & 3) << 4));
  const int lA = wr * 64 + (ra >> 1);       // A line base (+ i*8)
  const int lB = wcn * 32 + (ra >> 1);      // B line base (+ j*8)

  f32x4 acc[8][4];
#pragma unroll
  for (int i = 0; i < 8; ++i)
#pragma unroll
    for (int j = 0; j < 4; ++j)
#pragma unroll
      for (int r = 0; r < 4; ++r) acc[i][j][r] = 0.0f;

  const int NT = K >> 5;   // 32-wide K-tiles
  char* cb = lds;
  char* nb = lds + SLOT;

  // prologue: stage tile 0
  STAGE_ALL(cb, 0);
  asm volatile("s_waitcnt vmcnt(0)" ::: "memory");
  __builtin_amdgcn_sched_barrier(0);
  __builtin_amdgcn_s_barrier();

  for (int t = 0; t < NT; ++t) {
    if (t + 1 < NT) STAGE_ALL(nb, t + 1);   // prefetch next tile (6 gloads)
    __builtin_amdgcn_sched_barrier(0);      // pin stages before reads/MFMA

    bf16x8 afr[8], bfr[4];
#pragma unroll
    for (int i = 0; i < 8; ++i)
      afr[i] = *(const bf16x8*)(cb + (lA + i * 8) * 128 + swz);
#pragma unroll
    for (int j = 0; j < 4; ++j)
      bfr[j] = *(const bf16x8*)(cb + 16384 + (lB + j * 8) * 128 + swz);

    __builtin_amdgcn_s_setprio(1);
#pragma unroll
    for (int i = 0; i < 8; ++i)
#pragma unroll
      for (int j = 0; j < 4; ++j)
        acc[i][j] = __builtin_amdgcn_mfma_f32_16x16x32_bf16(afr[i], bfr[j],
                                                            acc[i][j], 0, 0, 0);
    __builtin_amdgcn_s_setprio(0);

    asm volatile("s_waitcnt vmcnt(0)" ::: "memory");  // next tile landed
    __builtin_amdgcn_sched_barrier(0);
    __builtin_amdgcn_s_barrier();
    char* tp = cb; cb = nb; nb = tp;
  }

  // epilogue: + bias, optional exact GELU, store
#pragma unroll
  for (int i = 0; i < 8; ++i) {
#pragma unroll
    for (int j = 0; j < 4; ++j) {
      int col = n0 + wcn * 64 + j * 16 + ra;
      float bv = bp[col];
#pragma unroll
      for (int r = 0; r < 4; ++r) {
        int row = m0 + wr * 128 + i * 16 + qa * 4 + r;
        float v = acc[i][j][r] + bv;
        if (GELU) v = 0.5f * v * (1.0f + erff(v * 0.70710678118654752f));
        if (C_F32)
          ((float*)Cptr)[(size_t)w * M * N + (size_t)row * N + col] = v;
        else
          ((u16*)Cptr)[(size_t)w * M * N + (size_t)row * N + col] =
              f32_to_bf16_rn(v);
      }
    }
  }
}

__global__ void bias_out_kernel(const float* __restrict__ b2,
                                float* __restrict__ outb) {
  int i = blockIdx.x * 256 + threadIdx.x;
  if (i < NW * HDIM) outb[i] = b2[i];
}

extern "C" void kernel_launch(void* const* d_in, const int* in_sizes, int n_in,
                              void* d_out, int out_size, void* d_ws,
                              size_t ws_size, hipStream_t stream) {
  const float* hs = (const float*)d_in[0];  // (8,2,1024,2048) f32
  const float* w1 = (const float*)d_in[1];  // (8,2048,1024) f32
  const float* b1 = (const float*)d_in[2];  // (8,1,1024) f32
  const float* w2 = (const float*)d_in[3];  // (8,1024,2048) f32
  const float* b2 = (const float*)d_in[4];  // (8,2048) f32

  // ws (u16): W1t (8,1024,2048) | W2t (8,2048,1024) | inter (8,2048,1024) | Xb (8,2048,2048)
  u16* W1t = (u16*)d_ws;
  u16* W2t = W1t + (size_t)NW * FFN * HDIM;
  u16* inter = W2t + (size_t)NW * HDIM * FFN;
  u16* XbWs = inter + (size_t)NW * MDIM * FFN;
  size_t need = ((size_t)NW * FFN * HDIM * 2 + (size_t)NW * MDIM * FFN +
                 (size_t)NW * MDIM * HDIM) * sizeof(u16);
  u16* Xb = (ws_size >= need) ? XbWs : (u16*)d_out;

  convert_bf16_kernel<<<dim3(NW * MDIM * HDIM / 4 / 256), 256, 0, stream>>>(hs, Xb);
  convert_transpose_kernel<<<dim3(FFN / 64, HDIM / 64, NW), 256, 0, stream>>>(
      w1, W1t, HDIM, FFN);
  convert_transpose_kernel<<<dim3(HDIM / 64, FFN / 64, NW), 256, 0, stream>>>(
      w2, W2t, FFN, HDIM);

  // inter = gelu(X @ W1 + b1)  [bf16]  M=2048 N=1024 K=2048 -> 512 blocks (2/CU)
  mlp_gemm<true, false>
      <<<dim3(NW * (MDIM / 256) * (FFN / 128)), 256, 0, stream>>>(
          Xb, W1t, b1, inter, MDIM, FFN, HDIM, FFN / 128);
  // out = inter @ W2 + b2  [f32]  M=2048 N=2048 K=1024 -> 1024 blocks
  mlp_gemm<false, true>
      <<<dim3(NW * (MDIM / 256) * (HDIM / 128)), 256, 0, stream>>>(
          inter, W2t, b2, d_out, MDIM, HDIM, FFN, HDIM / 128);

  float* outb = (float*)d_out + (size_t)NW * MDIM * HDIM;
  bias_out_kernel<<<dim3((NW * HDIM + 255) / 256), 256, 0, stream>>>(b2, outb);
}